// Round 1
// baseline (114.762 us; speedup 1.0000x reference)
//
#include <hip/hip_runtime.h>

// Chamfer distance, B=16 clouds x N=4096 points x D=3, fp32.
// total = (1/(B*N)) * [ sum_i min_j d(x_i,Y) + sum_j min_i d(y_j,X) ]
// d computed via the reference identity x^2 + y^2 - 2 x.y; x^2 is constant
// per query point so we track min_j (y^2 - 2 x.y) and add x^2 at the end.

namespace {

constexpr int kB = 16;
constexpr int kN = 4096;
constexpr int kNTH = 256;                 // threads per block
constexpr int kTILE = 256;                // y points staged in LDS per tile
constexpr int kPlane = kB * kN;           // 65536 query points per direction
constexpr float kScale = 1.0f / (float)(kB * kN);

__global__ void init_out(float* out) { out[0] = 0.0f; }

// One block: KX x-points per thread (kNTH*KX queries), scans one y-slice.
// DIRECT=true (S==1): full min computed -> block-reduce sum -> atomicAdd.
// DIRECT=false: store per-(slice, query) partial min to `part`.
template <int KX, int S, bool DIRECT>
__global__ __launch_bounds__(kNTH) void chamfer_min(
    const float* __restrict__ pred, const float* __restrict__ targ,
    float* __restrict__ part, float* __restrict__ out) {
  __shared__ float4 ytile[kTILE];

  const int t = threadIdx.x;
  const int xb = blockIdx.x;          // x-block within cloud
  const int b = blockIdx.y;           // cloud
  const int z = blockIdx.z;           // dir * S + slice
  const int dir = z / S;
  const int slice = z % S;

  const float* __restrict__ X = dir ? targ : pred;
  const float* __restrict__ Y = dir ? pred : targ;

  float xx[KX], xy[KX], xz[KX], x2[KX], mn[KX];
  const int ibase = b * kN + xb * (kNTH * KX) + t;
#pragma unroll
  for (int k = 0; k < KX; ++k) {
    const int i = ibase + k * kNTH;
    const float a = X[3 * i], c = X[3 * i + 1], d = X[3 * i + 2];
    xx[k] = a; xy[k] = c; xz[k] = d;
    x2[k] = fmaf(a, a, fmaf(c, c, d * d));
    mn[k] = 1e30f;
  }

  constexpr int YSL = kN / S;               // y points this block scans
  const int ybase = b * kN + slice * YSL;
  for (int t0 = 0; t0 < YSL; t0 += kTILE) {
    const int j = ybase + t0 + t;
    const float a = Y[3 * j], c = Y[3 * j + 1], d = Y[3 * j + 2];
    __syncthreads();  // protect previous tile's readers
    ytile[t] = make_float4(a, c, d, fmaf(a, a, fmaf(c, c, d * d)));
    __syncthreads();
#pragma unroll 8
    for (int jj = 0; jj < kTILE; ++jj) {
      const float4 q = ytile[jj];  // broadcast ds_read_b128, conflict-free
#pragma unroll
      for (int k = 0; k < KX; ++k) {
        const float dot = fmaf(xx[k], q.x, fmaf(xy[k], q.y, xz[k] * q.z));
        const float v = fmaf(-2.0f, dot, q.w);   // y^2 - 2 x.y
        mn[k] = fminf(mn[k], v);
      }
    }
  }

  if constexpr (DIRECT) {
    float s = 0.0f;
#pragma unroll
    for (int k = 0; k < KX; ++k) s += x2[k] + mn[k];
    for (int o = 32; o > 0; o >>= 1) s += __shfl_down(s, o, 64);
    __shared__ float wsum[kNTH / 64];
    const int lane = t & 63, w = t >> 6;
    if (lane == 0) wsum[w] = s;
    __syncthreads();
    if (t == 0) {
      float tot = 0.0f;
#pragma unroll
      for (int w2 = 0; w2 < kNTH / 64; ++w2) tot += wsum[w2];
      atomicAdd(out, tot * kScale);
    }
  } else {
#pragma unroll
    for (int k = 0; k < KX; ++k)
      part[(size_t)z * kPlane + (ibase + k * kNTH)] = x2[k] + mn[k];
  }
}

// Min over S slices per query, then global sum via per-block atomicAdd.
template <int S>
__global__ __launch_bounds__(256) void chamfer_reduce(
    const float* __restrict__ part, float* __restrict__ out) {
  const int u = blockIdx.x * 256 + threadIdx.x;   // [0, 2*kPlane)
  const int dir = u >> 16;                        // kPlane == 65536
  const int q = u & (kPlane - 1);
  float m = 1e30f;
#pragma unroll
  for (int s = 0; s < S; ++s)
    m = fminf(m, part[(size_t)(dir * S + s) * kPlane + q]);
  for (int o = 32; o > 0; o >>= 1) m += __shfl_down(m, o, 64);
  __shared__ float wsum[4];
  const int lane = threadIdx.x & 63, w = threadIdx.x >> 6;
  if (lane == 0) wsum[w] = m;
  __syncthreads();
  if (threadIdx.x == 0)
    atomicAdd(out, (wsum[0] + wsum[1] + wsum[2] + wsum[3]) * kScale);
}

}  // namespace

extern "C" void kernel_launch(void* const* d_in, const int* in_sizes, int n_in,
                              void* d_out, int out_size, void* d_ws,
                              size_t ws_size, hipStream_t stream) {
  const float* pred = (const float*)d_in[0];
  const float* targ = (const float*)d_in[1];
  float* out = (float*)d_out;
  float* part = (float*)d_ws;

  init_out<<<dim3(1), dim3(1), 0, stream>>>(out);

  constexpr int S = 4;    // y-slices -> 512 blocks, 2 blocks/CU
  constexpr int KX = 4;   // x-points/thread -> 1 LDS b128 read per 4 pairs
  const size_t need = (size_t)2 * S * kPlane * sizeof(float);
  if (ws_size >= need) {
    dim3 grid(kN / (kNTH * KX), kB, 2 * S);
    chamfer_min<KX, S, false><<<grid, kNTH, 0, stream>>>(pred, targ, part, out);
    chamfer_reduce<S><<<dim3(2 * kPlane / 256), 256, 0, stream>>>(part, out);
  } else {
    // Fallback: no workspace needed; fewer blocks but still correct.
    constexpr int KX2 = 2;
    dim3 grid(kN / (kNTH * KX2), kB, 2);
    chamfer_min<KX2, 1, true><<<grid, kNTH, 0, stream>>>(pred, targ, nullptr,
                                                         out);
  }
}

// Round 2
// 107.352 us; speedup vs baseline: 1.0690x; 1.0690x over previous
//
#include <hip/hip_runtime.h>

// Chamfer distance, B=16 clouds x N=4096 points x D=3, fp32.
// total = (1/(B*N)) * [ sum_i min_j d(x_i,Y) + sum_j min_i d(y_j,X) ]
// d = x^2 + y^2 - 2 x.y; x^2 is constant per query so we track
// min_j (y^2 + (-2x).y) and add x^2 at the end.
// Inner loop: 3 fma + 0.5 min3 per pair (x' = -2x folded at load).

namespace {

constexpr int kB = 16;
constexpr int kN = 4096;
constexpr int kNTH = 256;                 // threads per block
constexpr int kTILE = 256;                // y points staged in LDS per tile
constexpr int kPlane = kB * kN;           // 65536 query points per direction
constexpr float kScale = 1.0f / (float)(kB * kN);

__global__ void init_out(float* out) { out[0] = 0.0f; }

// One block: KX x-points per thread (kNTH*KX queries), scans one y-slice.
// DIRECT=true (S==1): full min computed -> block-reduce sum -> atomicAdd.
// DIRECT=false: store per-(slice, query) partial min to `part`.
template <int KX, int S, bool DIRECT>
__global__ __launch_bounds__(kNTH) void chamfer_min(
    const float* __restrict__ pred, const float* __restrict__ targ,
    float* __restrict__ part, float* __restrict__ out) {
  __shared__ float4 ytile[kTILE];

  const int t = threadIdx.x;
  const int xb = blockIdx.x;          // x-block within cloud
  const int b = blockIdx.y;           // cloud
  const int z = blockIdx.z;           // dir * S + slice
  const int dir = z / S;
  const int slice = z % S;

  const float* __restrict__ X = dir ? targ : pred;
  const float* __restrict__ Y = dir ? pred : targ;

  float xpx[KX], xpy[KX], xpz[KX], x2[KX], mn[KX];
  const int ibase = b * kN + xb * (kNTH * KX) + t;
#pragma unroll
  for (int k = 0; k < KX; ++k) {
    const int i = ibase + k * kNTH;
    const float a = X[3 * i], c = X[3 * i + 1], d = X[3 * i + 2];
    x2[k] = fmaf(a, a, fmaf(c, c, d * d));
    xpx[k] = -2.0f * a; xpy[k] = -2.0f * c; xpz[k] = -2.0f * d;
    mn[k] = 1e30f;
  }

  constexpr int YSL = kN / S;               // y points this block scans
  const int ybase = b * kN + slice * YSL;
  for (int t0 = 0; t0 < YSL; t0 += kTILE) {
    const int j = ybase + t0 + t;
    const float a = Y[3 * j], c = Y[3 * j + 1], d = Y[3 * j + 2];
    __syncthreads();  // protect previous tile's readers
    ytile[t] = make_float4(a, c, d, fmaf(a, a, fmaf(c, c, d * d)));
    __syncthreads();
#pragma unroll 4
    for (int jj = 0; jj < kTILE; jj += 2) {
      const float4 q0 = ytile[jj];      // broadcast ds_read_b128
      const float4 q1 = ytile[jj + 1];
#pragma unroll
      for (int k = 0; k < KX; ++k) {
        const float v0 =
            fmaf(xpx[k], q0.x, fmaf(xpy[k], q0.y, fmaf(xpz[k], q0.z, q0.w)));
        const float v1 =
            fmaf(xpx[k], q1.x, fmaf(xpy[k], q1.y, fmaf(xpz[k], q1.z, q1.w)));
        mn[k] = fminf(mn[k], fminf(v0, v1));   // -> v_min3_f32
      }
    }
  }

  if constexpr (DIRECT) {
    float s = 0.0f;
#pragma unroll
    for (int k = 0; k < KX; ++k) s += x2[k] + mn[k];
    for (int o = 32; o > 0; o >>= 1) s += __shfl_down(s, o, 64);
    __shared__ float wsum[kNTH / 64];
    const int lane = t & 63, w = t >> 6;
    if (lane == 0) wsum[w] = s;
    __syncthreads();
    if (t == 0) {
      float tot = 0.0f;
#pragma unroll
      for (int w2 = 0; w2 < kNTH / 64; ++w2) tot += wsum[w2];
      atomicAdd(out, tot * kScale);
    }
  } else {
#pragma unroll
    for (int k = 0; k < KX; ++k)
      part[(size_t)z * kPlane + (ibase + k * kNTH)] = x2[k] + mn[k];
  }
}

// Min over S slices per query, then global sum via per-block atomicAdd.
template <int S>
__global__ __launch_bounds__(256) void chamfer_reduce(
    const float* __restrict__ part, float* __restrict__ out) {
  const int u = blockIdx.x * 256 + threadIdx.x;   // [0, 2*kPlane)
  const int dir = u >> 16;                        // kPlane == 65536
  const int q = u & (kPlane - 1);
  float m = 1e30f;
#pragma unroll
  for (int s = 0; s < S; ++s)
    m = fminf(m, part[(size_t)(dir * S + s) * kPlane + q]);
  for (int o = 32; o > 0; o >>= 1) m += __shfl_down(m, o, 64);
  __shared__ float wsum[4];
  const int lane = threadIdx.x & 63, w = threadIdx.x >> 6;
  if (lane == 0) wsum[w] = m;
  __syncthreads();
  if (threadIdx.x == 0)
    atomicAdd(out, (wsum[0] + wsum[1] + wsum[2] + wsum[3]) * kScale);
}

}  // namespace

extern "C" void kernel_launch(void* const* d_in, const int* in_sizes, int n_in,
                              void* d_out, int out_size, void* d_ws,
                              size_t ws_size, hipStream_t stream) {
  const float* pred = (const float*)d_in[0];
  const float* targ = (const float*)d_in[1];
  float* out = (float*)d_out;
  float* part = (float*)d_ws;

  init_out<<<dim3(1), dim3(1), 0, stream>>>(out);

  constexpr int KX = 4;   // x-points/thread -> 1 LDS b128 read per 8 pairs
  const size_t need8 = (size_t)2 * 8 * kPlane * sizeof(float);   // 4 MB
  const size_t need4 = (size_t)2 * 4 * kPlane * sizeof(float);   // 2 MB
  if (ws_size >= need8) {
    constexpr int S = 8;  // 1024 blocks -> 4 blocks/CU, 16 waves/CU
    dim3 grid(kN / (kNTH * KX), kB, 2 * S);
    chamfer_min<KX, S, false><<<grid, kNTH, 0, stream>>>(pred, targ, part, out);
    chamfer_reduce<S><<<dim3(2 * kPlane / 256), 256, 0, stream>>>(part, out);
  } else if (ws_size >= need4) {
    constexpr int S = 4;  // 512 blocks -> 2 blocks/CU
    dim3 grid(kN / (kNTH * KX), kB, 2 * S);
    chamfer_min<KX, S, false><<<grid, kNTH, 0, stream>>>(pred, targ, part, out);
    chamfer_reduce<S><<<dim3(2 * kPlane / 256), 256, 0, stream>>>(part, out);
  } else {
    // Fallback: no workspace needed; fewer blocks but still correct.
    constexpr int KX2 = 2;
    dim3 grid(kN / (kNTH * KX2), kB, 2);
    chamfer_min<KX2, 1, true><<<grid, kNTH, 0, stream>>>(pred, targ, nullptr,
                                                         out);
  }
}